// Round 17
// baseline (244.572 us; speedup 1.0000x reference)
//
#include <hip/hip_runtime.h>

typedef __attribute__((ext_vector_type(8))) __bf16 bf16x8;
typedef __attribute__((ext_vector_type(4))) float f32x4;
typedef __attribute__((ext_vector_type(4))) unsigned int u32x4;

union FragU { u32x4 u; bf16x8 b; };
union BfBits { __bf16 b; unsigned short s; };

#define MFMA16(A, B, C) __builtin_amdgcn_mfma_f32_16x16x32_bf16((A), (B), (C), 0, 0, 0)

// SCALAR gelu only. R15 tried a float2 ext-vector version (v_pk_fma_f32 path):
// absmax blew up 1.22e-4 -> 4.46e-3 with algebraically identical math.
// Packed-f32 vector arithmetic is BANNED in this kernel (suspect ISel/opsel).
__device__ __forceinline__ float gelu_f(float x) {
    const float z = fabsf(x) * 0.70710678118654752440f;
    const float t = __builtin_amdgcn_rcpf(fmaf(0.3275911f, z, 1.0f));   // ~1ulp, 1 inst
    const float poly = t * (0.254829592f + t * (-0.284496736f + t * (1.421413741f +
                       t * (-1.453152027f + t * 1.061405429f))));
    const float e = 1.0f - poly * __expf(-z * z);
    const float s = copysignf(e, x);
    return 0.5f * x * (1.0f + s);
}

// Split 8 f32 into bf16 hi/lo planes; hi = round-half-away, lo = exact residual
// truncated. v_perm_b32 packs each pair in 1 inst.
__device__ __forceinline__ void split8(const float x0, const float x1, const float x2,
                                       const float x3, const float x4, const float x5,
                                       const float x6, const float x7,
                                       bf16x8& hi, bf16x8& lo) {
    const float xs[8] = {x0, x1, x2, x3, x4, x5, x6, x7};
    FragU H, L;
    #pragma unroll
    for (int p = 0; p < 4; ++p) {
        const unsigned int h0m = (__float_as_uint(xs[2*p])   + 0x8000u) & 0xFFFF0000u;
        const unsigned int h1m = (__float_as_uint(xs[2*p+1]) + 0x8000u) & 0xFFFF0000u;
        H.u[p] = __builtin_amdgcn_perm(h1m, h0m, 0x07060302);   // [hi(x0) | hi(x1)]
        const float r0 = xs[2*p]   - __uint_as_float(h0m);
        const float r1 = xs[2*p+1] - __uint_as_float(h1m);
        L.u[p] = __builtin_amdgcn_perm(__float_as_uint(r1), __float_as_uint(r0), 0x07060302);
    }
    hi = H.b; lo = L.b;
}

// ---------------------------------------------------------------------------
// Prep: swizzle weights into MFMA B-fragment order, bf16 hi/lo planes (RNE).
// Fragment elem (lane, i) = W[k = ks*32 + (lane>>4)*8 + i][n = nt*16 + (lane&15)]
// ws layout (ushort):
//   [0,4096)        W0f  [nt4][hl2][lane][8]   (b0 folded in at k==6)
//   [4096,12288)    W1f  [ks2][nt4][hl2][lane][8]
//   [12288,20480)   W2f  [ks2][nt4][hl2][lane][8]
//   [20480,53248)   pW1f [ks2][nt16][hl2][lane][8]
// ---------------------------------------------------------------------------
__global__ __launch_bounds__(256)
void prep_frags(const float* __restrict__ kW0, const float* __restrict__ kb0,
                const float* __restrict__ kW1, const float* __restrict__ kW2,
                const float* __restrict__ pW1,
                unsigned short* __restrict__ wsf)
{
    const int idx  = blockIdx.x * 256 + threadIdx.x;   // 0..53247
    const int i    = idx & 7;
    const int lane = (idx >> 3) & 63;
    float val;
    int hl;
    if (idx < 4096) {
        const int rest = idx >> 9;           // nt*2+hl
        hl = rest & 1;
        const int nt = rest >> 1;
        const int k = (lane >> 4) * 8 + i;
        const int n = nt * 16 + (lane & 15);
        val = (k < 6) ? kW0[k * 64 + n] : (k == 6 ? kb0[n] : 0.0f);
    } else if (idx < 12288) {
        const int rest = (idx - 4096) >> 9;  // (ks*4+nt)*2+hl
        hl = rest & 1;
        const int ntks = rest >> 1;
        const int nt = ntks & 3, ks = ntks >> 2;
        const int k = ks * 32 + (lane >> 4) * 8 + i;
        const int n = nt * 16 + (lane & 15);
        val = kW1[k * 64 + n];
    } else if (idx < 20480) {
        const int rest = (idx - 12288) >> 9;
        hl = rest & 1;
        const int ntks = rest >> 1;
        const int nt = ntks & 3, ks = ntks >> 2;
        const int k = ks * 32 + (lane >> 4) * 8 + i;
        const int n = nt * 16 + (lane & 15);
        val = kW2[k * 64 + n];
    } else {
        const int rest = (idx - 20480) >> 9; // (ks*16+nt)*2+hl
        hl = rest & 1;
        const int ntks = rest >> 1;
        const int nt = ntks & 15, ks = ntks >> 4;
        const int k = ks * 32 + (lane >> 4) * 8 + i;
        const int n = nt * 16 + (lane & 15);
        val = pW1[k * 256 + n];
    }
    BfBits hi; hi.b = (__bf16)val;
    unsigned short ob;
    if (hl == 0) ob = hi.s;
    else { BfBits lo; lo.b = (__bf16)(val - (float)hi.b); ob = lo.s; }
    wsf[idx] = ob;
}

// ---------------------------------------------------------------------------
// Main: wave = 1 query (16 edges) per t-step, 4 queries/wave, 4 waves/block.
// W1/W2 frags staged in LDS (32 KB); W0 frags in registers; pW1 from global.
// sdec stored PRE-SPLIT as packed bf16 hi/lo u32 planes [16][32].
// R17: t-loop UNROLL 2 + ping-pong sH buffers (sH[8], selector w*2+(t&1)).
//   Rationale: R13 proved extra waves don't help (3-wave-feasible config ==
//   2-wave dur) -> idle is INTRA-wave lgkmcnt serialization at the 3 LDS
//   round-trips per t-step. Unroll-2 gives the scheduler a second independent
//   query chain to fill those waits. LDS 71,680 B -> 2 blocks/CU (3rd block
//   was proven worthless). FETCH_SIZE >200MB = spill canary -> revert.
// R15 FAILED: packed-f32 (float2/v_pk) gelu -> absmax 4.46e-3; BANNED.
// OccupancyPercent is a gfx94x-formula fallback on gfx950 -- DO NOT TRUST.
// D-layout: col(=n)=lane&15, row(=m)=(lane>>4)*4 + reg.
// A-layout: row=lane&15, k  = (lane>>4)*8 + i.
// ---------------------------------------------------------------------------
__global__ __launch_bounds__(256, 2)
void gno_mfma(const float* __restrict__ rndata,   // [16000,64]
              const float* __restrict__ qpos,     // [100000,3]
              const float* __restrict__ latpos,   // [16000,3]
              const int*   __restrict__ edge_src, // [E]
              const float* __restrict__ kb1, const float* __restrict__ kb2,
              const float* __restrict__ pb1,
              const float* __restrict__ pW2, const float* __restrict__ pb2,
              const unsigned short* __restrict__ wsf,
              float* __restrict__ out)            // [100000,4]
{
    __shared__ __align__(16) u32x4 sWf[2048];     // 32 KB: W1 [0,1024), W2 [1024,2048)
    __shared__ __align__(16) float sH[8][16][68]; // 34816 B, 2 per wave (ping-pong)
    __shared__ __align__(16) unsigned int sdech[16][32];  // packed bf16-hi pairs, 2 KB
    __shared__ __align__(16) unsigned int sdecl[16][32];  // packed bf16-lo pairs, 2 KB

    const int tid = threadIdx.x;
    const u32x4* wv = (const u32x4*)wsf;   // global frags: W0 at f, pW1 at 2560+f

    #pragma unroll
    for (int i = 0; i < 8; ++i) sWf[i * 256 + tid] = wv[512 + i * 256 + tid];
    __syncthreads();

    const int l   = tid & 63;
    const int w   = tid >> 6;
    const int r15 = l & 15;
    const int g   = l >> 4;
    const int qbase = blockIdx.x * 16 + w * 4;

    float bv1[4], bv2[4];
    #pragma unroll
    for (int nt = 0; nt < 4; ++nt) {
        bv1[nt] = kb1[nt * 16 + r15];
        bv2[nt] = kb2[nt * 16 + r15];
    }

    // W0 fragments are t-invariant -- load once, hold in registers.
    FragU w0h[4], w0l[4];
    #pragma unroll
    for (int nt = 0; nt < 4; ++nt) {
        w0h[nt].u = wv[(nt * 2 + 0) * 64 + l];
        w0l[nt].u = wv[(nt * 2 + 1) * 64 + l];
    }

    // hoist srcv for all 4 t-steps (independent, coalesced-ish loads)
    int srcvA[4];
    #pragma unroll
    for (int t = 0; t < 4; ++t) srcvA[t] = edge_src[(qbase + t) * 16 + r15];

    #pragma unroll 2
    for (int t = 0; t < 4; ++t) {
        const int q = qbase + t;
        const int srcv = srcvA[t];
        float (*myH)[68] = sH[w * 2 + (t & 1)];   // ping-pong: t and t+1 independent

        // ---- prefetch: coords (needed in ~10 inst) then rndata (needed in ~700) ----
        const float lp0 = latpos[srcv * 3 + 0], lp1 = latpos[srcv * 3 + 1],
                    lp2 = latpos[srcv * 3 + 2];
        const float qp0 = qpos[q * 3 + 0], qp1 = qpos[q * 3 + 1], qp2 = qpos[q * 3 + 2];
        int se[4];
        #pragma unroll
        for (int r = 0; r < 4; ++r) se[r] = __shfl(srcv, g * 4 + r);
        float rnv[16];
        #pragma unroll
        for (int nt = 0; nt < 4; ++nt)
            #pragma unroll
            for (int r = 0; r < 4; ++r)
                rnv[nt * 4 + r] = rndata[(size_t)se[r] * 64 + nt * 16 + r15];

        // ---- layer 0: A-frag from coords (k-group 0 only), bias via k==6 ----
        const float m0 = (g == 0) ? 1.0f : 0.0f;
        bf16x8 a0h, a0l;
        split8(lp0 * m0, lp1 * m0, lp2 * m0, qp0 * m0, qp1 * m0, qp2 * m0,
               m0, 0.0f, a0h, a0l);
        #pragma unroll
        for (int nt = 0; nt < 4; ++nt) {
            f32x4 c = {0.f, 0.f, 0.f, 0.f};
            c = MFMA16(a0h, w0h[nt].b, c);
            c = MFMA16(a0l, w0h[nt].b, c);
            c = MFMA16(a0h, w0l[nt].b, c);
            #pragma unroll
            for (int j = 0; j < 4; ++j)
                myH[g * 4 + j][nt * 16 + r15] = gelu_f(c[j]);
        }

        // ---- layer 1: A from sH, GELU, overwrite sH ----
        bf16x8 a1h[2], a1l[2];
        #pragma unroll
        for (int ks = 0; ks < 2; ++ks) {
            const float* p = &myH[r15][ks * 32 + g * 8];
            const float4 xa = *(const float4*)p;
            const float4 xb = *(const float4*)(p + 4);
            split8(xa.x, xa.y, xa.z, xa.w, xb.x, xb.y, xb.z, xb.w, a1h[ks], a1l[ks]);
        }
        #pragma unroll
        for (int nt = 0; nt < 4; ++nt) {
            const float bv = bv1[nt];
            f32x4 c = {bv, bv, bv, bv};
            #pragma unroll
            for (int ks = 0; ks < 2; ++ks) {
                FragU wh, wl;
                wh.u = sWf[((ks * 4 + nt) * 2 + 0) * 64 + l];
                wl.u = sWf[((ks * 4 + nt) * 2 + 1) * 64 + l];
                c = MFMA16(a1h[ks], wh.b, c);
                c = MFMA16(a1l[ks], wh.b, c);
                c = MFMA16(a1h[ks], wl.b, c);
            }
            #pragma unroll
            for (int j = 0; j < 4; ++j)
                myH[g * 4 + j][nt * 16 + r15] = gelu_f(c[j]);
        }

        // ---- layer 2 (+ rep*rndata + 16-edge mean, split+pack at write) ----
        bf16x8 a2h[2], a2l[2];
        #pragma unroll
        for (int ks = 0; ks < 2; ++ks) {
            const float* p = &myH[r15][ks * 32 + g * 8];
            const float4 xa = *(const float4*)p;
            const float4 xb = *(const float4*)(p + 4);
            split8(xa.x, xa.y, xa.z, xa.w, xb.x, xb.y, xb.z, xb.w, a2h[ks], a2l[ks]);
        }
        #pragma unroll
        for (int nt = 0; nt < 4; ++nt) {
            const float bv = bv2[nt];
            f32x4 c = {bv, bv, bv, bv};
            #pragma unroll
            for (int ks = 0; ks < 2; ++ks) {
                FragU wh, wl;
                wh.u = sWf[1024 + ((ks * 4 + nt) * 2 + 0) * 64 + l];
                wl.u = sWf[1024 + ((ks * 4 + nt) * 2 + 1) * 64 + l];
                c = MFMA16(a2h[ks], wh.b, c);
                c = MFMA16(a2l[ks], wh.b, c);
                c = MFMA16(a2h[ks], wl.b, c);
            }
            float v = 0.0f;
            #pragma unroll
            for (int r = 0; r < 4; ++r)
                v += c[r] * rnv[nt * 4 + r];   // c[r] is edge (g*4+r), channel nt*16+r15
            v += __shfl_xor(v, 16);
            v += __shfl_xor(v, 32);
            // split to bf16 hi/lo and pack channel pairs (split8 math at write site)
            const float s = v * 0.0625f;
            const unsigned int sm = (__float_as_uint(s) + 0x8000u) & 0xFFFF0000u;
            const float sr = s - __uint_as_float(sm);
            const unsigned int smn = __shfl_xor(sm, 1);
            const float srn = __shfl_xor(sr, 1);
            if (l < 16 && (l & 1) == 0) {
                sdech[w * 4 + t][nt * 8 + (l >> 1)] =
                    __builtin_amdgcn_perm(smn, sm, 0x07060302);
                sdecl[w * 4 + t][nt * 8 + (l >> 1)] =
                    __builtin_amdgcn_perm(__float_as_uint(srn), __float_as_uint(sr), 0x07060302);
            }
        }
    }

    // ---- projection via MFMA: 16 block-queries = one M=16 tile ----
    __syncthreads();
    float (*spart)[16][4] = (float (*)[16][4])&sH[0][0][0];   // sH is dead; alias

    bf16x8 pah[2], pal[2];
    #pragma unroll
    for (int ks = 0; ks < 2; ++ks) {
        FragU PH, PL;
        PH.u = *(const u32x4*)&sdech[r15][ks * 16 + g * 4];
        PL.u = *(const u32x4*)&sdecl[r15][ks * 16 + g * 4];
        pah[ks] = PH.b; pal[ks] = PL.b;
    }

    float o[4][4];
    #pragma unroll
    for (int j = 0; j < 4; ++j)
        #pragma unroll
        for (int cc = 0; cc < 4; ++cc) o[j][cc] = 0.0f;

    #pragma unroll
    for (int ntl = 0; ntl < 4; ++ntl) {
        const int ntg = w * 4 + ntl;          // global 16-unit tile, 0..15
        f32x4 c = {0.f, 0.f, 0.f, 0.f};
        #pragma unroll
        for (int ks = 0; ks < 2; ++ks) {
            FragU wh, wl;
            wh.u = wv[2560 + ((ks * 16 + ntg) * 2 + 0) * 64 + l];
            wl.u = wv[2560 + ((ks * 16 + ntg) * 2 + 1) * 64 + l];
            c = MFMA16(pah[ks], wh.b, c);
            c = MFMA16(pal[ks], wh.b, c);
            c = MFMA16(pah[ks], wl.b, c);
        }
        const int u = ntg * 16 + r15;         // hidden unit 0..255
        const float bu = pb1[u];
        const float4 w2 = *(const float4*)&pW2[u * 4];
        #pragma unroll
        for (int j = 0; j < 4; ++j) {         // row j -> query g*4+j
            const float gv = gelu_f(c[j] + bu);
            o[j][0] += gv * w2.x; o[j][1] += gv * w2.y;
            o[j][2] += gv * w2.z; o[j][3] += gv * w2.w;
        }
    }
    #pragma unroll
    for (int j = 0; j < 4; ++j)
        #pragma unroll
        for (int cc = 0; cc < 4; ++cc) {
            o[j][cc] += __shfl_xor(o[j][cc], 1);
            o[j][cc] += __shfl_xor(o[j][cc], 2);
            o[j][cc] += __shfl_xor(o[j][cc], 4);
            o[j][cc] += __shfl_xor(o[j][cc], 8);
        }
    if (r15 == 0) {
        #pragma unroll
        for (int j = 0; j < 4; ++j)
            *(float4*)&spart[w][g * 4 + j][0] =
                make_float4(o[j][0], o[j][1], o[j][2], o[j][3]);
    }
    __syncthreads();

    if (tid < 64) {
        const int qq = tid >> 2, cc = tid & 3;
        const float val = spart[0][qq][cc] + spart[1][qq][cc]
                        + spart[2][qq][cc] + spart[3][qq][cc] + pb2[cc];
        out[(size_t)(blockIdx.x * 16 + qq) * 4 + cc] = val;
    }
}

extern "C" void kernel_launch(void* const* d_in, const int* in_sizes, int n_in,
                              void* d_out, int out_size, void* d_ws, size_t ws_size,
                              hipStream_t stream)
{
    const float* rndata = (const float*)d_in[0];
    const float* qpos   = (const float*)d_in[1];
    const float* latpos = (const float*)d_in[3];
    const int*   edge   = (const int*)d_in[5];
    const float* kW0 = (const float*)d_in[6];
    const float* kb0 = (const float*)d_in[7];
    const float* kW1 = (const float*)d_in[8];
    const float* kb1 = (const float*)d_in[9];
    const float* kW2 = (const float*)d_in[10];
    const float* kb2 = (const float*)d_in[11];
    const float* pW1 = (const float*)d_in[12];
    const float* pb1 = (const float*)d_in[13];
    const float* pW2 = (const float*)d_in[14];
    const float* pb2 = (const float*)d_in[15];
    float* out = (float*)d_out;

    const int E  = in_sizes[5] / 2;   // 1,600,000
    const int Nq = out_size / 4;      // 100,000

    prep_frags<<<208, 256, 0, stream>>>(kW0, kb0, kW1, kW2, pW1, (unsigned short*)d_ws);
    gno_mfma<<<Nq / 16, 256, 0, stream>>>(
        rndata, qpos, latpos, edge + E,
        kb1, kb2, pb1, pW2, pb2,
        (const unsigned short*)d_ws, out);
}

// Round 18
// 231.439 us; speedup vs baseline: 1.0567x; 1.0567x over previous
//
#include <hip/hip_runtime.h>

typedef __attribute__((ext_vector_type(8))) __bf16 bf16x8;
typedef __attribute__((ext_vector_type(4))) float f32x4;
typedef __attribute__((ext_vector_type(4))) unsigned int u32x4;

union FragU { u32x4 u; bf16x8 b; };
union BfBits { __bf16 b; unsigned short s; };

#define MFMA16(A, B, C) __builtin_amdgcn_mfma_f32_16x16x32_bf16((A), (B), (C), 0, 0, 0)

// SCALAR gelu only. R15 tried a float2 ext-vector version (v_pk_fma_f32 path):
// absmax blew up 1.22e-4 -> 4.46e-3 with algebraically identical math.
// Packed-f32 vector arithmetic is BANNED in this kernel (suspect ISel/opsel).
__device__ __forceinline__ float gelu_f(float x) {
    const float z = fabsf(x) * 0.70710678118654752440f;
    const float t = __builtin_amdgcn_rcpf(fmaf(0.3275911f, z, 1.0f));   // ~1ulp, 1 inst
    const float poly = t * (0.254829592f + t * (-0.284496736f + t * (1.421413741f +
                       t * (-1.453152027f + t * 1.061405429f))));
    const float e = 1.0f - poly * __expf(-z * z);
    const float s = copysignf(e, x);
    return 0.5f * x * (1.0f + s);
}

// Split 8 f32 into bf16 hi/lo planes; hi = round-half-away, lo = exact residual
// truncated. v_perm_b32 packs each pair in 1 inst.
__device__ __forceinline__ void split8(const float x0, const float x1, const float x2,
                                       const float x3, const float x4, const float x5,
                                       const float x6, const float x7,
                                       bf16x8& hi, bf16x8& lo) {
    const float xs[8] = {x0, x1, x2, x3, x4, x5, x6, x7};
    FragU H, L;
    #pragma unroll
    for (int p = 0; p < 4; ++p) {
        const unsigned int h0m = (__float_as_uint(xs[2*p])   + 0x8000u) & 0xFFFF0000u;
        const unsigned int h1m = (__float_as_uint(xs[2*p+1]) + 0x8000u) & 0xFFFF0000u;
        H.u[p] = __builtin_amdgcn_perm(h1m, h0m, 0x07060302);   // [hi(x0) | hi(x1)]
        const float r0 = xs[2*p]   - __uint_as_float(h0m);
        const float r1 = xs[2*p+1] - __uint_as_float(h1m);
        L.u[p] = __builtin_amdgcn_perm(__float_as_uint(r1), __float_as_uint(r0), 0x07060302);
    }
    hi = H.b; lo = L.b;
}

// ---------------------------------------------------------------------------
// Prep: swizzle weights into MFMA B-fragment order, bf16 hi/lo planes (RNE).
// Fragment elem (lane, i) = W[k = ks*32 + (lane>>4)*8 + i][n = nt*16 + (lane&15)]
// ws layout (ushort):
//   [0,4096)        W0f  [nt4][hl2][lane][8]   (b0 folded in at k==6)
//   [4096,12288)    W1f  [ks2][nt4][hl2][lane][8]
//   [12288,20480)   W2f  [ks2][nt4][hl2][lane][8]
//   [20480,53248)   pW1f [ks2][nt16][hl2][lane][8]
// ---------------------------------------------------------------------------
__global__ __launch_bounds__(256)
void prep_frags(const float* __restrict__ kW0, const float* __restrict__ kb0,
                const float* __restrict__ kW1, const float* __restrict__ kW2,
                const float* __restrict__ pW1,
                unsigned short* __restrict__ wsf)
{
    const int idx  = blockIdx.x * 256 + threadIdx.x;   // 0..53247
    const int i    = idx & 7;
    const int lane = (idx >> 3) & 63;
    float val;
    int hl;
    if (idx < 4096) {
        const int rest = idx >> 9;           // nt*2+hl
        hl = rest & 1;
        const int nt = rest >> 1;
        const int k = (lane >> 4) * 8 + i;
        const int n = nt * 16 + (lane & 15);
        val = (k < 6) ? kW0[k * 64 + n] : (k == 6 ? kb0[n] : 0.0f);
    } else if (idx < 12288) {
        const int rest = (idx - 4096) >> 9;  // (ks*4+nt)*2+hl
        hl = rest & 1;
        const int ntks = rest >> 1;
        const int nt = ntks & 3, ks = ntks >> 2;
        const int k = ks * 32 + (lane >> 4) * 8 + i;
        const int n = nt * 16 + (lane & 15);
        val = kW1[k * 64 + n];
    } else if (idx < 20480) {
        const int rest = (idx - 12288) >> 9;
        hl = rest & 1;
        const int ntks = rest >> 1;
        const int nt = ntks & 3, ks = ntks >> 2;
        const int k = ks * 32 + (lane >> 4) * 8 + i;
        const int n = nt * 16 + (lane & 15);
        val = kW2[k * 64 + n];
    } else {
        const int rest = (idx - 20480) >> 9; // (ks*16+nt)*2+hl
        hl = rest & 1;
        const int ntks = rest >> 1;
        const int nt = ntks & 15, ks = ntks >> 4;
        const int k = ks * 32 + (lane >> 4) * 8 + i;
        const int n = nt * 16 + (lane & 15);
        val = pW1[k * 256 + n];
    }
    BfBits hi; hi.b = (__bf16)val;
    unsigned short ob;
    if (hl == 0) ob = hi.s;
    else { BfBits lo; lo.b = (__bf16)(val - (float)hi.b); ob = lo.s; }
    wsf[idx] = ob;
}

// ---------------------------------------------------------------------------
// Main: wave = 1 query (16 edges) per t-step, 4 queries/wave, 4 waves/block.
// W1/W2 frags staged in LDS (32 KB); W0 frags in registers (t-invariant);
// pW1 frags from global. sdec stored PRE-SPLIT as packed bf16 hi/lo u32
// planes [16][32]. Proven-best configuration (R16, 231 us):
//   VALUBusy 67% + MfmaUtil 17.6% ~= 85% combined issue; floor is ~230M
//   exact-erf GELU evals (~20 slots each incl. quarter-rate exp/rcp).
// Dead-end ledger (do not retry):
//   R6/R9:  launch_bounds (256,4)/(256,3) on global-frag form -> scratch spill
//   R12/13: LDS diet + (256,3) on LDS-frag form -> occupancy unchanged, dur ==
//   R15:    packed-f32 (v_pk) gelu -> absmax 4.46e-3, BANNED
//   R17:    t-loop unroll-2 ping-pong -> VGPR cap 128 hit, spill, 245 us
// OccupancyPercent is a gfx94x-formula fallback on gfx950 -- DO NOT TRUST.
// D-layout: col(=n)=lane&15, row(=m)=(lane>>4)*4 + reg.
// A-layout: row=lane&15, k  = (lane>>4)*8 + i.
// ---------------------------------------------------------------------------
__global__ __launch_bounds__(256, 2)
void gno_mfma(const float* __restrict__ rndata,   // [16000,64]
              const float* __restrict__ qpos,     // [100000,3]
              const float* __restrict__ latpos,   // [16000,3]
              const int*   __restrict__ edge_src, // [E]
              const float* __restrict__ kb1, const float* __restrict__ kb2,
              const float* __restrict__ pb1,
              const float* __restrict__ pW2, const float* __restrict__ pb2,
              const unsigned short* __restrict__ wsf,
              float* __restrict__ out)            // [100000,4]
{
    __shared__ __align__(16) u32x4 sWf[2048];     // 32 KB: W1 [0,1024), W2 [1024,2048)
    __shared__ __align__(16) float sH[4][16][68]; // 17408 B (re-used as spart after t-loop)
    __shared__ __align__(16) unsigned int sdech[16][32];  // packed bf16-hi pairs, 2 KB
    __shared__ __align__(16) unsigned int sdecl[16][32];  // packed bf16-lo pairs, 2 KB

    const int tid = threadIdx.x;
    const u32x4* wv = (const u32x4*)wsf;   // global frags: W0 at f, pW1 at 2560+f

    #pragma unroll
    for (int i = 0; i < 8; ++i) sWf[i * 256 + tid] = wv[512 + i * 256 + tid];
    __syncthreads();

    const int l   = tid & 63;
    const int w   = tid >> 6;
    const int r15 = l & 15;
    const int g   = l >> 4;
    const int qbase = blockIdx.x * 16 + w * 4;

    float bv1[4], bv2[4];
    #pragma unroll
    for (int nt = 0; nt < 4; ++nt) {
        bv1[nt] = kb1[nt * 16 + r15];
        bv2[nt] = kb2[nt * 16 + r15];
    }

    // W0 fragments are t-invariant -- load once, hold in registers.
    FragU w0h[4], w0l[4];
    #pragma unroll
    for (int nt = 0; nt < 4; ++nt) {
        w0h[nt].u = wv[(nt * 2 + 0) * 64 + l];
        w0l[nt].u = wv[(nt * 2 + 1) * 64 + l];
    }

    // hoist srcv for all 4 t-steps (independent, coalesced-ish loads)
    int srcvA[4];
    #pragma unroll
    for (int t = 0; t < 4; ++t) srcvA[t] = edge_src[(qbase + t) * 16 + r15];

    float (*myH)[68] = sH[w];

    #pragma unroll 1
    for (int t = 0; t < 4; ++t) {
        const int q = qbase + t;
        const int srcv = srcvA[t];

        // ---- prefetch: coords (needed in ~10 inst) then rndata (needed in ~700) ----
        const float lp0 = latpos[srcv * 3 + 0], lp1 = latpos[srcv * 3 + 1],
                    lp2 = latpos[srcv * 3 + 2];
        const float qp0 = qpos[q * 3 + 0], qp1 = qpos[q * 3 + 1], qp2 = qpos[q * 3 + 2];
        int se[4];
        #pragma unroll
        for (int r = 0; r < 4; ++r) se[r] = __shfl(srcv, g * 4 + r);
        float rnv[16];
        #pragma unroll
        for (int nt = 0; nt < 4; ++nt)
            #pragma unroll
            for (int r = 0; r < 4; ++r)
                rnv[nt * 4 + r] = rndata[(size_t)se[r] * 64 + nt * 16 + r15];

        // ---- layer 0: A-frag from coords (k-group 0 only), bias via k==6 ----
        const float m0 = (g == 0) ? 1.0f : 0.0f;
        bf16x8 a0h, a0l;
        split8(lp0 * m0, lp1 * m0, lp2 * m0, qp0 * m0, qp1 * m0, qp2 * m0,
               m0, 0.0f, a0h, a0l);
        #pragma unroll
        for (int nt = 0; nt < 4; ++nt) {
            f32x4 c = {0.f, 0.f, 0.f, 0.f};
            c = MFMA16(a0h, w0h[nt].b, c);
            c = MFMA16(a0l, w0h[nt].b, c);
            c = MFMA16(a0h, w0l[nt].b, c);
            #pragma unroll
            for (int j = 0; j < 4; ++j)
                myH[g * 4 + j][nt * 16 + r15] = gelu_f(c[j]);
        }

        // ---- layer 1: A from sH, GELU, overwrite sH ----
        bf16x8 a1h[2], a1l[2];
        #pragma unroll
        for (int ks = 0; ks < 2; ++ks) {
            const float* p = &myH[r15][ks * 32 + g * 8];
            const float4 xa = *(const float4*)p;
            const float4 xb = *(const float4*)(p + 4);
            split8(xa.x, xa.y, xa.z, xa.w, xb.x, xb.y, xb.z, xb.w, a1h[ks], a1l[ks]);
        }
        #pragma unroll
        for (int nt = 0; nt < 4; ++nt) {
            const float bv = bv1[nt];
            f32x4 c = {bv, bv, bv, bv};
            #pragma unroll
            for (int ks = 0; ks < 2; ++ks) {
                FragU wh, wl;
                wh.u = sWf[((ks * 4 + nt) * 2 + 0) * 64 + l];
                wl.u = sWf[((ks * 4 + nt) * 2 + 1) * 64 + l];
                c = MFMA16(a1h[ks], wh.b, c);
                c = MFMA16(a1l[ks], wh.b, c);
                c = MFMA16(a1h[ks], wl.b, c);
            }
            #pragma unroll
            for (int j = 0; j < 4; ++j)
                myH[g * 4 + j][nt * 16 + r15] = gelu_f(c[j]);
        }

        // ---- layer 2 (+ rep*rndata + 16-edge mean, split+pack at write) ----
        bf16x8 a2h[2], a2l[2];
        #pragma unroll
        for (int ks = 0; ks < 2; ++ks) {
            const float* p = &myH[r15][ks * 32 + g * 8];
            const float4 xa = *(const float4*)p;
            const float4 xb = *(const float4*)(p + 4);
            split8(xa.x, xa.y, xa.z, xa.w, xb.x, xb.y, xb.z, xb.w, a2h[ks], a2l[ks]);
        }
        #pragma unroll
        for (int nt = 0; nt < 4; ++nt) {
            const float bv = bv2[nt];
            f32x4 c = {bv, bv, bv, bv};
            #pragma unroll
            for (int ks = 0; ks < 2; ++ks) {
                FragU wh, wl;
                wh.u = sWf[1024 + ((ks * 4 + nt) * 2 + 0) * 64 + l];
                wl.u = sWf[1024 + ((ks * 4 + nt) * 2 + 1) * 64 + l];
                c = MFMA16(a2h[ks], wh.b, c);
                c = MFMA16(a2l[ks], wh.b, c);
                c = MFMA16(a2h[ks], wl.b, c);
            }
            float v = 0.0f;
            #pragma unroll
            for (int r = 0; r < 4; ++r)
                v += c[r] * rnv[nt * 4 + r];   // c[r] is edge (g*4+r), channel nt*16+r15
            v += __shfl_xor(v, 16);
            v += __shfl_xor(v, 32);
            // split to bf16 hi/lo and pack channel pairs (split8 math at write site)
            const float s = v * 0.0625f;
            const unsigned int sm = (__float_as_uint(s) + 0x8000u) & 0xFFFF0000u;
            const float sr = s - __uint_as_float(sm);
            const unsigned int smn = __shfl_xor(sm, 1);
            const float srn = __shfl_xor(sr, 1);
            if (l < 16 && (l & 1) == 0) {
                sdech[w * 4 + t][nt * 8 + (l >> 1)] =
                    __builtin_amdgcn_perm(smn, sm, 0x07060302);
                sdecl[w * 4 + t][nt * 8 + (l >> 1)] =
                    __builtin_amdgcn_perm(__float_as_uint(srn), __float_as_uint(sr), 0x07060302);
            }
        }
    }

    // ---- projection via MFMA: 16 block-queries = one M=16 tile ----
    __syncthreads();
    float (*spart)[16][4] = (float (*)[16][4])&sH[0][0][0];   // sH is dead; alias

    bf16x8 pah[2], pal[2];
    #pragma unroll
    for (int ks = 0; ks < 2; ++ks) {
        FragU PH, PL;
        PH.u = *(const u32x4*)&sdech[r15][ks * 16 + g * 4];
        PL.u = *(const u32x4*)&sdecl[r15][ks * 16 + g * 4];
        pah[ks] = PH.b; pal[ks] = PL.b;
    }

    float o[4][4];
    #pragma unroll
    for (int j = 0; j < 4; ++j)
        #pragma unroll
        for (int cc = 0; cc < 4; ++cc) o[j][cc] = 0.0f;

    #pragma unroll
    for (int ntl = 0; ntl < 4; ++ntl) {
        const int ntg = w * 4 + ntl;          // global 16-unit tile, 0..15
        f32x4 c = {0.f, 0.f, 0.f, 0.f};
        #pragma unroll
        for (int ks = 0; ks < 2; ++ks) {
            FragU wh, wl;
            wh.u = wv[2560 + ((ks * 16 + ntg) * 2 + 0) * 64 + l];
            wl.u = wv[2560 + ((ks * 16 + ntg) * 2 + 1) * 64 + l];
            c = MFMA16(pah[ks], wh.b, c);
            c = MFMA16(pal[ks], wh.b, c);
            c = MFMA16(pah[ks], wl.b, c);
        }
        const int u = ntg * 16 + r15;         // hidden unit 0..255
        const float bu = pb1[u];
        const float4 w2 = *(const float4*)&pW2[u * 4];
        #pragma unroll
        for (int j = 0; j < 4; ++j) {         // row j -> query g*4+j
            const float gv = gelu_f(c[j] + bu);
            o[j][0] += gv * w2.x; o[j][1] += gv * w2.y;
            o[j][2] += gv * w2.z; o[j][3] += gv * w2.w;
        }
    }
    #pragma unroll
    for (int j = 0; j < 4; ++j)
        #pragma unroll
        for (int cc = 0; cc < 4; ++cc) {
            o[j][cc] += __shfl_xor(o[j][cc], 1);
            o[j][cc] += __shfl_xor(o[j][cc], 2);
            o[j][cc] += __shfl_xor(o[j][cc], 4);
            o[j][cc] += __shfl_xor(o[j][cc], 8);
        }
    if (r15 == 0) {
        #pragma unroll
        for (int j = 0; j < 4; ++j)
            *(float4*)&spart[w][g * 4 + j][0] =
                make_float4(o[j][0], o[j][1], o[j][2], o[j][3]);
    }
    __syncthreads();

    if (tid < 64) {
        const int qq = tid >> 2, cc = tid & 3;
        const float val = spart[0][qq][cc] + spart[1][qq][cc]
                        + spart[2][qq][cc] + spart[3][qq][cc] + pb2[cc];
        out[(size_t)(blockIdx.x * 16 + qq) * 4 + cc] = val;
    }
}

extern "C" void kernel_launch(void* const* d_in, const int* in_sizes, int n_in,
                              void* d_out, int out_size, void* d_ws, size_t ws_size,
                              hipStream_t stream)
{
    const float* rndata = (const float*)d_in[0];
    const float* qpos   = (const float*)d_in[1];
    const float* latpos = (const float*)d_in[3];
    const int*   edge   = (const int*)d_in[5];
    const float* kW0 = (const float*)d_in[6];
    const float* kb0 = (const float*)d_in[7];
    const float* kW1 = (const float*)d_in[8];
    const float* kb1 = (const float*)d_in[9];
    const float* kW2 = (const float*)d_in[10];
    const float* kb2 = (const float*)d_in[11];
    const float* pW1 = (const float*)d_in[12];
    const float* pb1 = (const float*)d_in[13];
    const float* pW2 = (const float*)d_in[14];
    const float* pb2 = (const float*)d_in[15];
    float* out = (float*)d_out;

    const int E  = in_sizes[5] / 2;   // 1,600,000
    const int Nq = out_size / 4;      // 100,000

    prep_frags<<<208, 256, 0, stream>>>(kW0, kb0, kW1, kW2, pW1, (unsigned short*)d_ws);
    gno_mfma<<<Nq / 16, 256, 0, stream>>>(
        rndata, qpos, latpos, edge + E,
        kb1, kb2, pb1, pW2, pb2,
        (const unsigned short*)d_ws, out);
}